// Round 4
// baseline (238.127 us; speedup 1.0000x reference)
//
#include <hip/hip_runtime.h>

// STDP learner: tr_pre/tr_post elementwise + delta_w = 0.5*w*(conv-wgrad pair).
// delta_w[o,i,kh,kw] = 0.5*w[o,i,kh,kw] *
//   sum_{b,p,q} tpre[b,i,p+kh,q+kw]*out[b,o,p,q] - tpost[b,o,p,q]*in[b,i,p+kh,q+kw]
// Sizes: B=16 CIN=64 H=W=66 COUT=128 HO=WO=64 KH=KW=3
// out layout: [tr_pre 4460544][tr_post 8388608][delta_w 73728]
//
// R9: revert R8 (per-lane B loads -> 640 scattered 8B VMEM ops, regressed
// 85->121us). Base = R7 structure (k_main 85us = 238MB @ 2.9TB/s, traffic-
// bound). Delete bytes: split-K 128 -> 32.
//  - MFMA block now covers 32 p-rows (4x stages) and HALF the o-range
//    (mt=1, acc 48 regs): 192 blocks = 3 kh x 16 b x 2 o-half x 2 p-chunk.
//  - partials: 37.7MB -> 9.4MB (write once, k_finalize reads 9.4 not 37.7):
//    ~56MB less HBM round-trip.
//  - Stage structure verbatim R7: B (tpre,in) fp32->cvt->LDS double-buffered,
//    1 barrier/stage; A (out,tpost) global->reg, cvt at use.
//  - fill roles merged as before; k_finalize now sums 32 slices.

typedef unsigned short ushort_t;
typedef unsigned int uint_t;
typedef __attribute__((ext_vector_type(8))) short short8;
typedef __attribute__((ext_vector_type(4))) float floatx4;
typedef __attribute__((ext_vector_type(2))) float floatx2;
typedef __attribute__((ext_vector_type(4))) int intx4;
typedef __attribute__((ext_vector_type(4))) uint_t uintx4;

#define N_POST   8388608     // 16*128*64*64
#define N_DW     73728       // 128*64*9
#define O_TRPOST 4460544
#define O_DW     12849152

#define MFMA_BLOCKS  192     // 3 kh * (16 b * 2 o-half * 2 p-chunk)
#define FILLA_BLOCKS 1024
#define FILLB_BLOCKS 768
#define TOTAL_BLOCKS 1984
#define B_ROWS_PER_WAVE 22   // 768*4*22 = 67584 rows exactly
#define NSPLIT 32            // split-K slices per (kh,kw): 16 b x 2 p-chunk

// packed fp32->bf16, HW RNE (same rounding as bit-twiddle f2bf)
__device__ __forceinline__ int cvt2bf(float lo, float hi) {
  int r; asm("v_cvt_pk_bf16_f32 %0, %1, %2" : "=v"(r) : "v"(lo), "v"(hi)); return r;
}
__device__ __forceinline__ int cvt2bfn(float lo, float hi) {   // negated (free VOP3 mods)
  int r; asm("v_cvt_pk_bf16_f32 %0, -%1, -%2" : "=v"(r) : "v"(lo), "v"(hi)); return r;
}
// bytes [2..5] of (hi:lo) -- one v_alignbit_b32
__device__ __forceinline__ int bsh2(int hi, int lo) {
  return (int)((((unsigned long long)(uint_t)hi << 32) | (uint_t)lo) >> 16);
}

// ---- merged kernel ---------------------------------------------------------
// bx < 192:        MFMA role (needs ws for partials)
// 192..1216:       elementwise tr_post (float4 grid-stride, 8 iters exact)
// 1216..1984:      elementwise tr_pre (wave-per-row, lanes 0..32 x float2)
__global__ __launch_bounds__(256, 2)
void k_main(const float* __restrict__ in_sp, const float* __restrict__ out_sp,
            const float* __restrict__ tpre, const float* __restrict__ tpost,
            float* __restrict__ o_trpre, float* __restrict__ o_trpost,
            float* __restrict__ partials, int use_ws) {
  const int bx0 = blockIdx.x;
  const int t = threadIdx.x;

  if (bx0 >= MFMA_BLOCKS) {
    if (bx0 < MFMA_BLOCKS + FILLA_BLOCKS) {
      int i4 = (bx0 - MFMA_BLOCKS) * 256 + t;          // 2097152 = 262144*8
      #pragma unroll
      for (int it = 0; it < 8; ++it, i4 += FILLA_BLOCKS * 256) {
        floatx4 o = *(const floatx4*)(out_sp + i4 * 4);
        floatx4 p = *(const floatx4*)(tpost + i4 * 4);
        *(floatx4*)(o_trpost + i4 * 4) = 0.5f * p + o;
      }
    } else {
      const int l = t & 63;
      if (l >= 33) return;
      const int wid = (bx0 - (MFMA_BLOCKS + FILLA_BLOCKS)) * 4 + (t >> 6);
      #pragma unroll 2
      for (int it = 0; it < B_ROWS_PER_WAVE; ++it) {
        const int g = (wid * B_ROWS_PER_WAVE + it) * 66 + l * 2;
        floatx2 a = *(const floatx2*)(tpre + g);
        floatx2 c = *(const floatx2*)(in_sp + g);
        floatx2 v = { 0.5f * a.x + c.x, 0.5f * a.y + c.y };
        *(floatx2*)(o_trpre + g) = v;
      }
    }
    return;
  }
  if (!use_ws) return;                                 // fallback handles dw

  // ---- MFMA role: bx0 -> kh = bx0>>6; r=bx0&63 -> b=r>>2, half=(r>>1)&1,
  // pc=r&1 (p0 = pc*32). block 256 = 4 waves, wave w owns o in
  // [half*64 + w*16, +16). 32 stages (one p-row each):
  //   A (out,tpost): 8x dwordx4 global->reg, cvt at use. No LDS (no reuse).
  //   B (tpre,in): 64 i-rows x 66 fp32 -> cvt -> LDS, double-buffered.
  // LB layout: [buf][i][mat*72 + e] shorts, row stride 304B (2-way banks=free)
  __shared__ short LB[2][9728];                        // 38 KB
  const int kh = bx0 >> 6, r = bx0 & 63;
  const int b = r >> 2, half = (r >> 1) & 1, pc = r & 1;
  const int p0 = pc * 32;
  const int w = t >> 6, l = t & 63;
  const int quad = l >> 4, l16 = l & 15;
  const int si = t >> 2, sg = t & 3;                   // B-stage: i row, 16-col seg

  const float* arow0 = out_sp + ((b * 128 + half * 64 + w * 16 + l16) * 4096 + quad * 8 + p0 * 64);
  const float* arow1 = tpost  + ((b * 128 + half * 64 + w * 16 + l16) * 4096 + quad * 8 + p0 * 64);
  const float* brow0 = tpre  + ((b * 64 + si) * 4356 + sg * 16);
  const float* brow1 = in_sp + ((b * 64 + si) * 4356 + sg * 16);
  short* Lrow = &LB[0][0] + si * 152 + sg * 16;        // + buf*9728 + mat*72

  floatx4 acc[3][4] = {};                              // [kw][nt]

  auto stageB = [&](int h, int buf) {
    const float* r0 = brow0 + h * 66;
    const float* r1 = brow1 + h * 66;
    floatx2 v0[8], v1[8];
    #pragma unroll
    for (int k = 0; k < 8; ++k) {                      // rows only 8B-aligned
      v0[k] = *(const floatx2*)(r0 + 2 * k);
      v1[k] = *(const floatx2*)(r1 + 2 * k);
    }
    uintx4 u0a = { (uint_t)cvt2bf(v0[0].x, v0[0].y), (uint_t)cvt2bf(v0[1].x, v0[1].y),
                   (uint_t)cvt2bf(v0[2].x, v0[2].y), (uint_t)cvt2bf(v0[3].x, v0[3].y) };
    uintx4 u0b = { (uint_t)cvt2bf(v0[4].x, v0[4].y), (uint_t)cvt2bf(v0[5].x, v0[5].y),
                   (uint_t)cvt2bf(v0[6].x, v0[6].y), (uint_t)cvt2bf(v0[7].x, v0[7].y) };
    uintx4 u1a = { (uint_t)cvt2bf(v1[0].x, v1[0].y), (uint_t)cvt2bf(v1[1].x, v1[1].y),
                   (uint_t)cvt2bf(v1[2].x, v1[2].y), (uint_t)cvt2bf(v1[3].x, v1[3].y) };
    uintx4 u1b = { (uint_t)cvt2bf(v1[4].x, v1[4].y), (uint_t)cvt2bf(v1[5].x, v1[5].y),
                   (uint_t)cvt2bf(v1[6].x, v1[6].y), (uint_t)cvt2bf(v1[7].x, v1[7].y) };
    short* Lb = Lrow + buf * 9728;
    *(uintx4*)(Lb)      = u0a;                         // mat0 = tpre
    *(uintx4*)(Lb + 8)  = u0b;
    *(uintx4*)(Lb + 72) = u1a;                         // mat1 = in
    *(uintx4*)(Lb + 80) = u1b;
    if (sg == 3) {                                     // elems 64,65
      floatx2 t0 = *(const floatx2*)(r0 + 16);
      floatx2 t1 = *(const floatx2*)(r1 + 16);
      *(uint_t*)(Lb + 16) = (uint_t)cvt2bf(t0.x, t0.y);
      *(uint_t*)(Lb + 88) = (uint_t)cvt2bf(t1.x, t1.y);
    }
  };

  stageB(p0 + kh, 0);
  __syncthreads();

  for (int rr = 0; rr < 32; ++rr) {
    // A loads for this stage (issued first; latency hides under B staging)
    floatx4 ar[2][2][2];                               // [mat][ks][half]
    #pragma unroll
    for (int ks = 0; ks < 2; ++ks)
      #pragma unroll
      for (int hf = 0; hf < 2; ++hf) {
        const int off = rr * 64 + ks * 32 + hf * 4;
        ar[0][ks][hf] = *(const floatx4*)(arow0 + off);
        ar[1][ks][hf] = *(const floatx4*)(arow1 + off);
      }
    if (rr < 31) stageB(p0 + rr + 1 + kh, (rr + 1) & 1);

    const short* Lbb = &LB[0][0] + (rr & 1) * 9728;
    #pragma unroll
    for (int ks = 0; ks < 2; ++ks) {
      short8 fa[2];                                    // [mat]
      {
        uintx4 ua = { (uint_t)cvt2bf (ar[0][ks][0].x, ar[0][ks][0].y),
                      (uint_t)cvt2bf (ar[0][ks][0].z, ar[0][ks][0].w),
                      (uint_t)cvt2bf (ar[0][ks][1].x, ar[0][ks][1].y),
                      (uint_t)cvt2bf (ar[0][ks][1].z, ar[0][ks][1].w) };
        uintx4 un = { (uint_t)cvt2bfn(ar[1][ks][0].x, ar[1][ks][0].y),
                      (uint_t)cvt2bfn(ar[1][ks][0].z, ar[1][ks][0].w),
                      (uint_t)cvt2bfn(ar[1][ks][1].x, ar[1][ks][1].y),
                      (uint_t)cvt2bfn(ar[1][ks][1].z, ar[1][ks][1].w) };
        fa[0] = __builtin_bit_cast(short8, ua);        // A1 = out
        fa[1] = __builtin_bit_cast(short8, un);        // A2 = -tpost
      }
      #pragma unroll
      for (int nt = 0; nt < 4; ++nt) {
        const int i = nt * 16 + l16;
        short8 fb[2][3];                               // [mat][kw]
        #pragma unroll
        for (int mat = 0; mat < 2; ++mat) {
          const int base = i * 152 + mat * 72 + ks * 32 + quad * 8;
          intx4 W = *(const intx4*)&Lbb[base];
          int W4 = *(const int*)&Lbb[base + 8];
          intx4 f0 = { W.x, W.y, W.z, W.w };
          intx4 f1 = { bsh2(W.y, W.x), bsh2(W.z, W.y), bsh2(W.w, W.z), bsh2(W4, W.w) };
          intx4 f2 = { W.y, W.z, W.w, W4 };
          fb[mat][0] = __builtin_bit_cast(short8, f0);
          fb[mat][1] = __builtin_bit_cast(short8, f1);
          fb[mat][2] = __builtin_bit_cast(short8, f2);
        }
        #pragma unroll
        for (int kw = 0; kw < 3; ++kw) {
          acc[kw][nt] = __builtin_amdgcn_mfma_f32_16x16x32_bf16(fa[0], fb[0][kw], acc[kw][nt], 0, 0, 0);
          acc[kw][nt] = __builtin_amdgcn_mfma_f32_16x16x32_bf16(fa[1], fb[1][kw], acc[kw][nt], 0, 0, 0);
        }
      }
    }
    __syncthreads();                                   // buf reuse fence
  }

  // C/D layout: col(i)=lane&15, row(o within 16)=quad*4+reg (HW-verified)
  #pragma unroll
  for (int kw = 0; kw < 3; ++kw) {
    float* slice = partials + (size_t)((kh * 3 + kw) * NSPLIT + b * 2 + pc) * 8192;
    #pragma unroll
    for (int nt = 0; nt < 4; ++nt)
      #pragma unroll
      for (int rg = 0; rg < 4; ++rg) {
        const int o = half * 64 + w * 16 + quad * 4 + rg;
        const int i = nt * 16 + l16;
        slice[o * 64 + i] = acc[kw][nt][rg];
      }
  }
}

// ---- split-K reduction + finalize ------------------------------------------
__global__ void k_finalize(const float* __restrict__ partials,
                           const float* __restrict__ weight, float* __restrict__ dw) {
  int tid = blockIdx.x * 256 + threadIdx.x;            // < 73728
  int e = tid >> 13, oi = tid & 8191;
  float s = 0.f;
  #pragma unroll 8
  for (int c = 0; c < NSPLIT; ++c) s += partials[(size_t)(e * NSPLIT + c) * 8192 + oi];
  int o = oi >> 6, i = oi & 63;
  int wi = (o * 64 + i) * 9 + e;
  dw[wi] = 0.5f * weight[wi] * s;
}

// ---- fallback (ws too small): slow fp32, zero scratch ----------------------
__global__ void k_naive(const float* __restrict__ out_sp, const float* __restrict__ tpost,
                        const float* __restrict__ tpre, const float* __restrict__ in_sp,
                        const float* __restrict__ weight, float* __restrict__ dw) {
  int tid = blockIdx.x * 256 + threadIdx.x;
  int e = tid >> 13, oi = tid & 8191;
  int o = oi >> 6, i = oi & 63;
  int kh = e / 3, kw = e - kh * 3;
  float acc = 0.f;
  for (int b = 0; b < 16; ++b)
    for (int p = 0; p < 64; ++p) {
      const float* ga = out_sp + ((b * 128 + o) * 64 + p) * 64;
      const float* gn = tpost + ((b * 128 + o) * 64 + p) * 64;
      const float* gb = tpre + ((b * 64 + i) * 66 + p + kh) * 66 + kw;
      const float* gm = in_sp + ((b * 64 + i) * 66 + p + kh) * 66 + kw;
      for (int q = 0; q < 64; ++q) acc += ga[q] * gb[q] - gn[q] * gm[q];
    }
  int wi = (o * 64 + i) * 9 + kh * 3 + kw;
  dw[wi] = 0.5f * weight[wi] * acc;
}

extern "C" void kernel_launch(void* const* d_in, const int* in_sizes, int n_in,
                              void* d_out, int out_size, void* d_ws, size_t ws_size,
                              hipStream_t stream) {
  const float* in_sp  = (const float*)d_in[0];
  const float* out_sp = (const float*)d_in[1];
  const float* tpre   = (const float*)d_in[2];
  const float* tpost  = (const float*)d_in[3];
  const float* weight = (const float*)d_in[4];
  float* out = (float*)d_out;
  float* o_trpre  = out;
  float* o_trpost = out + O_TRPOST;
  float* o_dw     = out + O_DW;

  // ws: partials only (9*32*8192 fp32 = 9.4MB)
  const size_t WS_NEED = (size_t)9 * NSPLIT * 8192 * 4;
  const int use_mfma = (ws_size >= WS_NEED) ? 1 : 0;
  float* partials = (float*)d_ws;

  k_main<<<TOTAL_BLOCKS, 256, 0, stream>>>(in_sp, out_sp, tpre, tpost,
                                           o_trpre, o_trpost, partials, use_mfma);
  if (use_mfma) {
    k_finalize<<<N_DW / 256, 256, 0, stream>>>(partials, weight, o_dw);
  } else {
    k_naive<<<N_DW / 256, 256, 0, stream>>>(out_sp, tpost, tpre, in_sp, weight, o_dw);
  }
}

// Round 6
// 204.220 us; speedup vs baseline: 1.1660x; 1.1660x over previous
//
#include <hip/hip_runtime.h>

// STDP learner: tr_pre/tr_post elementwise + delta_w = 0.5*w*(conv-wgrad pair).
// delta_w[o,i,kh,kw] = 0.5*w[o,i,kh,kw] *
//   sum_{b,p,q} tpre[b,i,p+kh,q+kw]*out[b,o,p,q] - tpost[b,o,p,q]*in[b,i,p+kh,q+kw]
// Sizes: B=16 CIN=64 H=W=66 COUT=128 HO=WO=64 KH=KW=3
// out layout: [tr_pre 4460544][tr_post 8388608][delta_w 73728]
//
// R11: revert R10's lgkm-only barrier (raced: absmax 1.16; flat-op LDS stores
// are not fully covered by lgkmcnt(0) -- __syncthreads' vmcnt0+lgkm0 is what
// made R7 safe) and the XCD swizzle (no-op: kh-twins at bx+128/+256 are
// already same XCD mod 8). Base = R7 verbatim (proven 85.7us).
// One safe change: NON-TEMPORAL hints on the fill role's 154MB streams
// (touched once; keep them out of L2 so the mfma twins' shared A/B lines
// stay resident) + NT loads of partials in k_finalize (read-once).

typedef unsigned short ushort_t;
typedef unsigned int uint_t;
typedef __attribute__((ext_vector_type(8))) short short8;
typedef __attribute__((ext_vector_type(4))) float floatx4;
typedef __attribute__((ext_vector_type(2))) float floatx2;
typedef __attribute__((ext_vector_type(4))) int intx4;
typedef __attribute__((ext_vector_type(4))) uint_t uintx4;

#define N_POST   8388608     // 16*128*64*64
#define N_DW     73728       // 128*64*9
#define O_TRPOST 4460544
#define O_DW     12849152

#define MFMA_BLOCKS  384     // 3 kh * 128 (b,p0)
#define FILLA_BLOCKS 1024
#define FILLB_BLOCKS 768
#define TOTAL_BLOCKS 2176
#define B_ROWS_PER_WAVE 22   // 768*4*22 = 67584 rows exactly

// packed fp32->bf16, HW RNE (same rounding as bit-twiddle f2bf)
__device__ __forceinline__ int cvt2bf(float lo, float hi) {
  int r; asm("v_cvt_pk_bf16_f32 %0, %1, %2" : "=v"(r) : "v"(lo), "v"(hi)); return r;
}
__device__ __forceinline__ int cvt2bfn(float lo, float hi) {   // negated (free VOP3 mods)
  int r; asm("v_cvt_pk_bf16_f32 %0, -%1, -%2" : "=v"(r) : "v"(lo), "v"(hi)); return r;
}
// bytes [2..5] of (hi:lo) -- one v_alignbit_b32
__device__ __forceinline__ int bsh2(int hi, int lo) {
  return (int)((((unsigned long long)(uint_t)hi << 32) | (uint_t)lo) >> 16);
}

// ---- merged kernel ---------------------------------------------------------
// bx < 384:        MFMA role (needs ws for partials)
// 384..1408:       elementwise tr_post (float4 grid-stride, 8 iters exact)
// 1408..2176:      elementwise tr_pre (wave-per-row, lanes 0..32 x float2)
__global__ __launch_bounds__(256, 2)
void k_main(const float* __restrict__ in_sp, const float* __restrict__ out_sp,
            const float* __restrict__ tpre, const float* __restrict__ tpost,
            float* __restrict__ o_trpre, float* __restrict__ o_trpost,
            float* __restrict__ partials, int use_ws) {
  const int bx0 = blockIdx.x;
  const int t = threadIdx.x;

  if (bx0 >= MFMA_BLOCKS) {
    if (bx0 < MFMA_BLOCKS + FILLA_BLOCKS) {
      int i4 = (bx0 - MFMA_BLOCKS) * 256 + t;          // 2097152 = 262144*8
      #pragma unroll
      for (int it = 0; it < 8; ++it, i4 += FILLA_BLOCKS * 256) {
        floatx4 o = __builtin_nontemporal_load((const floatx4*)(out_sp + i4 * 4));
        floatx4 p = __builtin_nontemporal_load((const floatx4*)(tpost + i4 * 4));
        floatx4 v = 0.5f * p + o;
        __builtin_nontemporal_store(v, (floatx4*)(o_trpost + i4 * 4));
      }
    } else {
      const int l = t & 63;
      if (l >= 33) return;
      const int wid = (bx0 - (MFMA_BLOCKS + FILLA_BLOCKS)) * 4 + (t >> 6);
      #pragma unroll 2
      for (int it = 0; it < B_ROWS_PER_WAVE; ++it) {
        const int g = (wid * B_ROWS_PER_WAVE + it) * 66 + l * 2;
        floatx2 a = __builtin_nontemporal_load((const floatx2*)(tpre + g));
        floatx2 c = __builtin_nontemporal_load((const floatx2*)(in_sp + g));
        floatx2 v = { 0.5f * a.x + c.x, 0.5f * a.y + c.y };
        __builtin_nontemporal_store(v, (floatx2*)(o_trpre + g));
      }
    }
    return;
  }
  if (!use_ws) return;                                 // fallback handles dw

  // ---- MFMA role: grid x -> kh = bx0>>7, bx = bx0&127 -> b = bx>>3, p0
  // block 256 = 4 waves, wave w owns o in [w*32, w*32+32). Per stage (p-row):
  //   A (out,tpost): 16x dwordx4 global->reg, cvt at use. No LDS (no reuse).
  //   B (tpre,in): 64 i-rows x 66 fp32 -> cvt -> LDS, double-buffered.
  // LB layout: [buf][i][mat*72 + e] shorts, row stride 304B (2-way banks=free)
  __shared__ short LB[2][9728];                        // 38 KB
  const int kh = bx0 >> 7, bx = bx0 & 127;
  const int b = bx >> 3, p0 = (bx & 7) * 8;
  const int w = t >> 6, l = t & 63;
  const int quad = l >> 4, l16 = l & 15;
  const int si = t >> 2, sg = t & 3;                   // B-stage: i row, 16-col seg

  const float* arow0 = out_sp + ((b * 128 + w * 32 + l16) * 4096 + quad * 8 + p0 * 64);
  const float* arow1 = tpost  + ((b * 128 + w * 32 + l16) * 4096 + quad * 8 + p0 * 64);
  const float* brow0 = tpre  + ((b * 64 + si) * 4356 + sg * 16);
  const float* brow1 = in_sp + ((b * 64 + si) * 4356 + sg * 16);
  short* Lrow = &LB[0][0] + si * 152 + sg * 16;        // + buf*9728 + mat*72

  floatx4 acc[3][2][4] = {};                           // [kw][mt][nt]

  auto stageB = [&](int h, int buf) {
    const float* r0 = brow0 + h * 66;
    const float* r1 = brow1 + h * 66;
    floatx2 v0[8], v1[8];
    #pragma unroll
    for (int k = 0; k < 8; ++k) {                      // rows only 8B-aligned
      v0[k] = *(const floatx2*)(r0 + 2 * k);
      v1[k] = *(const floatx2*)(r1 + 2 * k);
    }
    uintx4 u0a = { (uint_t)cvt2bf(v0[0].x, v0[0].y), (uint_t)cvt2bf(v0[1].x, v0[1].y),
                   (uint_t)cvt2bf(v0[2].x, v0[2].y), (uint_t)cvt2bf(v0[3].x, v0[3].y) };
    uintx4 u0b = { (uint_t)cvt2bf(v0[4].x, v0[4].y), (uint_t)cvt2bf(v0[5].x, v0[5].y),
                   (uint_t)cvt2bf(v0[6].x, v0[6].y), (uint_t)cvt2bf(v0[7].x, v0[7].y) };
    uintx4 u1a = { (uint_t)cvt2bf(v1[0].x, v1[0].y), (uint_t)cvt2bf(v1[1].x, v1[1].y),
                   (uint_t)cvt2bf(v1[2].x, v1[2].y), (uint_t)cvt2bf(v1[3].x, v1[3].y) };
    uintx4 u1b = { (uint_t)cvt2bf(v1[4].x, v1[4].y), (uint_t)cvt2bf(v1[5].x, v1[5].y),
                   (uint_t)cvt2bf(v1[6].x, v1[6].y), (uint_t)cvt2bf(v1[7].x, v1[7].y) };
    short* Lb = Lrow + buf * 9728;
    *(uintx4*)(Lb)      = u0a;                         // mat0 = tpre
    *(uintx4*)(Lb + 8)  = u0b;
    *(uintx4*)(Lb + 72) = u1a;                         // mat1 = in
    *(uintx4*)(Lb + 80) = u1b;
    if (sg == 3) {                                     // elems 64,65
      floatx2 t0 = *(const floatx2*)(r0 + 16);
      floatx2 t1 = *(const floatx2*)(r1 + 16);
      *(uint_t*)(Lb + 16) = (uint_t)cvt2bf(t0.x, t0.y);
      *(uint_t*)(Lb + 88) = (uint_t)cvt2bf(t1.x, t1.y);
    }
  };

  stageB(p0 + kh, 0);
  __syncthreads();

  for (int rr = 0; rr < 8; ++rr) {
    // A loads for this stage (issued first; latency hides under B staging)
    floatx4 ar[2][2][2][2];                            // [mat][mt][ks][half]
    #pragma unroll
    for (int mt = 0; mt < 2; ++mt)
      #pragma unroll
      for (int ks = 0; ks < 2; ++ks)
        #pragma unroll
        for (int hf = 0; hf < 2; ++hf) {
          const int off = rr * 64 + mt * 65536 + ks * 32 + hf * 4;
          ar[0][mt][ks][hf] = *(const floatx4*)(arow0 + off);
          ar[1][mt][ks][hf] = *(const floatx4*)(arow1 + off);
        }
    if (rr < 7) stageB(p0 + rr + 1 + kh, (rr + 1) & 1);

    const short* Lbb = &LB[0][0] + (rr & 1) * 9728;
    #pragma unroll
    for (int ks = 0; ks < 2; ++ks) {
      short8 fa[2][2];                                 // [mat][mt]
      #pragma unroll
      for (int mt = 0; mt < 2; ++mt) {
        uintx4 ua = { (uint_t)cvt2bf (ar[0][mt][ks][0].x, ar[0][mt][ks][0].y),
                      (uint_t)cvt2bf (ar[0][mt][ks][0].z, ar[0][mt][ks][0].w),
                      (uint_t)cvt2bf (ar[0][mt][ks][1].x, ar[0][mt][ks][1].y),
                      (uint_t)cvt2bf (ar[0][mt][ks][1].z, ar[0][mt][ks][1].w) };
        uintx4 un = { (uint_t)cvt2bfn(ar[1][mt][ks][0].x, ar[1][mt][ks][0].y),
                      (uint_t)cvt2bfn(ar[1][mt][ks][0].z, ar[1][mt][ks][0].w),
                      (uint_t)cvt2bfn(ar[1][mt][ks][1].x, ar[1][mt][ks][1].y),
                      (uint_t)cvt2bfn(ar[1][mt][ks][1].z, ar[1][mt][ks][1].w) };
        fa[0][mt] = __builtin_bit_cast(short8, ua);    // A1 = out
        fa[1][mt] = __builtin_bit_cast(short8, un);    // A2 = -tpost
      }
      #pragma unroll
      for (int nt = 0; nt < 4; ++nt) {
        const int i = nt * 16 + l16;
        short8 fb[2][3];                               // [mat][kw]
        #pragma unroll
        for (int mat = 0; mat < 2; ++mat) {
          const int base = i * 152 + mat * 72 + ks * 32 + quad * 8;
          intx4 W = *(const intx4*)&Lbb[base];
          int W4 = *(const int*)&Lbb[base + 8];
          intx4 f0 = { W.x, W.y, W.z, W.w };
          intx4 f1 = { bsh2(W.y, W.x), bsh2(W.z, W.y), bsh2(W.w, W.z), bsh2(W4, W.w) };
          intx4 f2 = { W.y, W.z, W.w, W4 };
          fb[mat][0] = __builtin_bit_cast(short8, f0);
          fb[mat][1] = __builtin_bit_cast(short8, f1);
          fb[mat][2] = __builtin_bit_cast(short8, f2);
        }
        #pragma unroll
        for (int kw = 0; kw < 3; ++kw)
          #pragma unroll
          for (int mt = 0; mt < 2; ++mt) {
            acc[kw][mt][nt] = __builtin_amdgcn_mfma_f32_16x16x32_bf16(fa[0][mt], fb[0][kw], acc[kw][mt][nt], 0, 0, 0);
            acc[kw][mt][nt] = __builtin_amdgcn_mfma_f32_16x16x32_bf16(fa[1][mt], fb[1][kw], acc[kw][mt][nt], 0, 0, 0);
          }
      }
    }
    __syncthreads();                                   // buf reuse fence
  }

  // C/D layout: col(i)=lane&15, row(o within 16)=quad*4+reg (HW-verified)
  #pragma unroll
  for (int kw = 0; kw < 3; ++kw) {
    float* slice = partials + (size_t)((kh * 3 + kw) * 128 + bx) * 8192;
    #pragma unroll
    for (int mt = 0; mt < 2; ++mt)
      #pragma unroll
      for (int nt = 0; nt < 4; ++nt)
        #pragma unroll
        for (int rg = 0; rg < 4; ++rg) {
          const int o = w * 32 + mt * 16 + quad * 4 + rg;
          const int i = nt * 16 + l16;
          slice[o * 64 + i] = acc[kw][mt][nt][rg];
        }
  }
}

// ---- split-K reduction + finalize ------------------------------------------
__global__ void k_finalize(const float* __restrict__ partials,
                           const float* __restrict__ weight, float* __restrict__ dw) {
  int tid = blockIdx.x * 256 + threadIdx.x;            // < 73728
  int e = tid >> 13, oi = tid & 8191;
  float s = 0.f;
  #pragma unroll 8
  for (int c = 0; c < 128; ++c)
    s += __builtin_nontemporal_load(partials + (size_t)(e * 128 + c) * 8192 + oi);
  int o = oi >> 6, i = oi & 63;
  int wi = (o * 64 + i) * 9 + e;
  dw[wi] = 0.5f * weight[wi] * s;
}

// ---- fallback (ws too small): slow fp32, zero scratch ----------------------
__global__ void k_naive(const float* __restrict__ out_sp, const float* __restrict__ tpost,
                        const float* __restrict__ tpre, const float* __restrict__ in_sp,
                        const float* __restrict__ weight, float* __restrict__ dw) {
  int tid = blockIdx.x * 256 + threadIdx.x;
  int e = tid >> 13, oi = tid & 8191;
  int o = oi >> 6, i = oi & 63;
  int kh = e / 3, kw = e - kh * 3;
  float acc = 0.f;
  for (int b = 0; b < 16; ++b)
    for (int p = 0; p < 64; ++p) {
      const float* ga = out_sp + ((b * 128 + o) * 64 + p) * 64;
      const float* gn = tpost + ((b * 128 + o) * 64 + p) * 64;
      const float* gb = tpre + ((b * 64 + i) * 66 + p + kh) * 66 + kw;
      const float* gm = in_sp + ((b * 64 + i) * 66 + p + kh) * 66 + kw;
      for (int q = 0; q < 64; ++q) acc += ga[q] * gb[q] - gn[q] * gm[q];
    }
  int wi = (o * 64 + i) * 9 + kh * 3 + kw;
  dw[wi] = 0.5f * weight[wi] * acc;
}

extern "C" void kernel_launch(void* const* d_in, const int* in_sizes, int n_in,
                              void* d_out, int out_size, void* d_ws, size_t ws_size,
                              hipStream_t stream) {
  const float* in_sp  = (const float*)d_in[0];
  const float* out_sp = (const float*)d_in[1];
  const float* tpre   = (const float*)d_in[2];
  const float* tpost  = (const float*)d_in[3];
  const float* weight = (const float*)d_in[4];
  float* out = (float*)d_out;
  float* o_trpre  = out;
  float* o_trpost = out + O_TRPOST;
  float* o_dw     = out + O_DW;

  // ws: partials only (9*128*8192 fp32 = 37.7MB)
  const size_t WS_NEED = (size_t)9 * 128 * 8192 * 4;
  const int use_mfma = (ws_size >= WS_NEED) ? 1 : 0;
  float* partials = (float*)d_ws;

  k_main<<<TOTAL_BLOCKS, 256, 0, stream>>>(in_sp, out_sp, tpre, tpost,
                                           o_trpre, o_trpost, partials, use_mfma);
  if (use_mfma) {
    k_finalize<<<N_DW / 256, 256, 0, stream>>>(partials, weight, o_dw);
  } else {
    k_naive<<<N_DW / 256, 256, 0, stream>>>(out_sp, tpost, tpre, in_sp, weight, o_dw);
  }
}